// Round 4
// baseline (252.829 us; speedup 1.0000x reference)
//
#include <hip/hip_runtime.h>

#define NP 81
#define CC 128
#define HH 128
#define WW 256
#define YP 136
#define XP 288
#define WS_NEED 40108032ull   // 32 * 136 * 288 * 32 bytes

typedef __attribute__((ext_vector_type(8))) short short8;
typedef __attribute__((ext_vector_type(4))) float f32x4;

__device__ __forceinline__ short f2bf(float f) {
    unsigned int u = __builtin_bit_cast(unsigned int, f);
    u += 0x7fffu + ((u >> 16) & 1u);   // round-to-nearest-even
    return (short)(u >> 16);
}

// ---- pre-pass: t2 fp32 [b][c][h][w] -> ws bf16 [b][cg8][yp136][xp288][c16],
// halo zero-padded. 2 consecutive xp per thread: 512B read segs, 64B stores.
__global__ __launch_bounds__(256) void prepass_t2(const float* __restrict__ t2,
                                                  short* __restrict__ ws) {
    const int u  = blockIdx.x * 256 + threadIdx.x;   // 32*136*144 threads
    const int xh = u % 144;
    const int v  = u / 144;
    const int yp = v % YP;
    const int bc = v / YP;                            // b*8 + cg
    const int y2 = yp - 4;
    const int x2 = xh * 2 - 4;
    short8 a0 = {0,0,0,0,0,0,0,0}, a1 = a0, b0 = a0, b1 = a0;
    if (y2 >= 0 && y2 < HH) {
        const int b = bc >> 3, cg = bc & 7;
        const size_t pl = (size_t)HH * WW;
        const float* p = t2 + ((size_t)(b * CC + cg * 16) * HH + y2) * WW + x2;
        if (x2 >= 0 && x2 < WW) {
#pragma unroll
            for (int j = 0; j < 8; j++) { a0[j] = f2bf(p[(size_t)j * pl]);
                                          a1[j] = f2bf(p[(size_t)(j + 8) * pl]); }
        }
        if (x2 + 1 >= 0 && x2 + 1 < WW) {
#pragma unroll
            for (int j = 0; j < 8; j++) { b0[j] = f2bf(p[1 + (size_t)j * pl]);
                                          b1[j] = f2bf(p[1 + (size_t)(j + 8) * pl]); }
        }
    }
    short* o = ws + (size_t)u * 32;
    *(short8*)(o)      = a0;  *(short8*)(o + 8)  = a1;
    *(short8*)(o + 16) = b0;  *(short8*)(o + 24) = b1;
}

// ---- main: 16x16x32 MFMA band scheme. 512 thr / 8 waves (packs 2/SIMD).
// Block = (b, y, 16-x tile); 9 di-tasks, wave w does di=w, wave 0 also di=8.
// All 4 K-chunks' B fragments preloaded per task (one latency exposure).
__global__ __launch_bounds__(512, 7) void corr16_v3(const float* __restrict__ t1,
                                                    const short* __restrict__ ws,
                                                    float* __restrict__ out) {
    const int id = blockIdx.x;
    const int xt = id & 15;
    const int y  = (id >> 4) & (HH - 1);
    const int b  = id >> 11;
    const int X0 = xt * 16;

    const int tid  = threadIdx.x;
    const int lane = tid & 63;
    const int w    = tid >> 6;      // 0..7
    const int nl   = lane & 15;     // A row m / B col n'
    const int q    = lane >> 4;     // 0..3 k-quad

    __shared__ short sA[16 * 128];        // 4 KB, XOR-swizzled [x][c]
    __shared__ float obuf[NP * 24];       // 7.8 KB epilogue transpose

    const size_t plane = (size_t)HH * WW;

    // stage A: 16 x * 128 c, one short8 per thread (tid < 256)
    if (tid < 256) {
        const int x = tid & 15, oct = tid >> 4;   // oct = c/8
        const float* p = t1 + ((size_t)(b * CC + oct * 8) * HH + y) * WW + X0 + x;
        short8 pk;
#pragma unroll
        for (int j = 0; j < 8; j++) pk[j] = f2bf(p[(size_t)j * plane]);
        *(short8*)&sA[x * 128 + ((oct ^ x) * 8)] = pk;
    }

    // B fragment lane offset: chunk kc covers c = kc*32 + q*8 + j
    const size_t cs = (size_t)YP * XP * 16;       // shorts per cg16 slab
    const size_t rb_lane = (size_t)(q >> 1) * cs
                         + (size_t)(X0 + nl) * 16 + (q & 1) * 8;

    int di = w;
    size_t rowb = ((size_t)(b * 8) * YP + (y + di)) * XP * 16 + rb_lane;

    short8 B0[4], B1[4];
#pragma unroll
    for (int kc = 0; kc < 4; ++kc) {
        B0[kc] = *(const short8*)(ws + rowb + (size_t)kc * 2 * cs);
        B1[kc] = *(const short8*)(ws + rowb + (size_t)kc * 2 * cs + 256);
    }

    __syncthreads();

    const int ntask = (w == 0) ? 2 : 1;
    for (int pass = 0; pass < ntask; ++pass) {
        f32x4 a0 = {0.f, 0.f, 0.f, 0.f}, a1 = {0.f, 0.f, 0.f, 0.f};
#pragma unroll
        for (int kc = 0; kc < 4; ++kc) {
            const short8 af = *(const short8*)
                &sA[nl * 128 + (((kc * 4 + q) ^ nl) * 8)];
            a0 = __builtin_amdgcn_mfma_f32_16x16x32_bf16(af, B0[kc], a0, 0, 0, 0);
            a1 = __builtin_amdgcn_mfma_f32_16x16x32_bf16(af, B1[kc], a1, 0, 0, 0);
        }
        // band-extract: D row m = q*4+r (out x), col nl; dj = nl - m + 16t
#pragma unroll
        for (int r = 0; r < 4; ++r) {
            const int m  = q * 4 + r;
            const int d0 = nl - m;
            const int d1 = nl - m + 16;
            if (d0 >= 0 && d0 <= 8) obuf[(di * 9 + d0) * 24 + m] = a0[r];
            if (d1 <= 8)            obuf[(di * 9 + d1) * 24 + m] = a1[r];
        }
        if (pass + 1 < ntask) {   // wave 0: second task di = 8
            di = 8;
            rowb = ((size_t)(b * 8) * YP + (y + 8)) * XP * 16 + rb_lane;
#pragma unroll
            for (int kc = 0; kc < 4; ++kc) {
                B0[kc] = *(const short8*)(ws + rowb + (size_t)kc * 2 * cs);
                B1[kc] = *(const short8*)(ws + rowb + (size_t)kc * 2 * cs + 256);
            }
        }
    }

    __syncthreads();
    if (tid < 324) {                               // 81 p * 4 float4
        const int p = tid >> 2, xq = tid & 3;
        const f32x4 vv = *(const f32x4*)&obuf[p * 24 + xq * 4];
        *(f32x4*)&out[((size_t)(b * NP + p) * HH + y) * WW + X0 + xq * 4] = vv;
    }
}

// ---------------- fallback (proven R1 kernel) if ws is too small ----------------
__global__ __launch_bounds__(256) void corr_mfma_kernel(
        const float* __restrict__ t1, const float* __restrict__ t2,
        float* __restrict__ out) {
    const int id = blockIdx.x;
    const int xt = id & 3;
    const int y  = (id >> 2) & (HH - 1);
    const int b  = id >> 9;
    const int X0 = xt * 64;
    const int tid  = threadIdx.x;
    const int lane = tid & 63;
    const int wv   = tid >> 6;
    const int n    = lane & 15;
    const int q    = lane >> 4;
    __shared__ short smem[2560 + 28800];
    short* sA = smem;
    short* sB = smem + 2560;
    f32x4 acc[9][2];
#pragma unroll
    for (int i = 0; i < 9; i++)
#pragma unroll
        for (int t = 0; t < 2; t++) acc[i][t] = (f32x4){0.f, 0.f, 0.f, 0.f};
    const size_t plane = (size_t)HH * WW;
    const float* t1b = t1 + (size_t)b * CC * plane + (size_t)y * WW;
    const float* t2b = t2 + (size_t)b * CC * plane;
    for (int c0 = 0; c0 < CC; c0 += 32) {
        __syncthreads();
        {
            const int x  = tid & 63;
            const int cg = tid >> 6;
            const float* p = t1b + (size_t)(c0 + cg * 8) * plane + X0 + x;
            short8 pk;
#pragma unroll
            for (int j = 0; j < 8; j++) pk[j] = f2bf(p[(size_t)j * plane]);
            *(short8*)&sA[x * 40 + cg * 8] = pk;
        }
#pragma unroll
        for (int i = 0; i < 12; i++) {
            const int u = tid + i * 256;
            if (u < 2880) {
                const int r   = u / 320;
                const int rem = u - r * 320;
                const int cg  = rem / 80;
                const int ix  = rem - cg * 80;
                const int y2  = y + r - 4;
                const int x2  = X0 - 4 + ix;
                short8 pk;
                if (y2 >= 0 && y2 < HH && x2 >= 0 && x2 < WW) {
                    const float* p = t2b + (size_t)(c0 + cg * 8) * plane
                                   + (size_t)y2 * WW + x2;
#pragma unroll
                    for (int j = 0; j < 8; j++) pk[j] = f2bf(p[(size_t)j * plane]);
                } else {
#pragma unroll
                    for (int j = 0; j < 8; j++) pk[j] = 0;
                }
                *(short8*)&sB[r * 3200 + ix * 40 + cg * 8] = pk;
            }
        }
        __syncthreads();
        const short8 af = *(const short8*)&sA[(16 * wv + n) * 40 + q * 8];
#pragma unroll
        for (int di = 0; di < 9; di++) {
#pragma unroll
            for (int t = 0; t < 2; t++) {
                const short8 bf = *(const short8*)
                    &sB[di * 3200 + (16 * wv + 16 * t + n) * 40 + q * 8];
                acc[di][t] = __builtin_amdgcn_mfma_f32_16x16x32_bf16(
                    af, bf, acc[di][t], 0, 0, 0);
            }
        }
    }
    __syncthreads();
    float* obuf = (float*)smem;
#pragma unroll
    for (int di = 0; di < 9; di++)
#pragma unroll
        for (int t = 0; t < 2; t++)
#pragma unroll
            for (int r = 0; r < 4; r++) {
                const int m  = q * 4 + r;
                const int dj = n - m + 16 * t;
                if (dj >= 0 && dj <= 8)
                    obuf[(di * 9 + dj) * 68 + 16 * wv + m] = acc[di][t][r];
            }
    __syncthreads();
    float* ob = out + (size_t)b * NP * plane + (size_t)y * WW + X0;
#pragma unroll
    for (int i = 0; i < 6; i++) {
        const int u = tid + i * 256;
        if (u < 1296) {
            const int p  = u >> 4;
            const int xu = u & 15;
            f32x4 v = *(const f32x4*)&obuf[p * 68 + xu * 4];
            *(f32x4*)&ob[(size_t)p * plane + xu * 4] = v;
        }
    }
}

extern "C" void kernel_launch(void* const* d_in, const int* in_sizes, int n_in,
                              void* d_out, int out_size, void* d_ws, size_t ws_size,
                              hipStream_t stream) {
    const float* t1 = (const float*)d_in[0];
    const float* t2 = (const float*)d_in[1];
    float* out = (float*)d_out;
    if (ws_size >= WS_NEED) {
        short* ws = (short*)d_ws;
        prepass_t2<<<2448, 256, 0, stream>>>(t2, ws);     // 2448*256 = 32*136*144
        corr16_v3<<<8192, 512, 0, stream>>>(t1, ws, out); // 4b*128y*16xt
    } else {
        corr_mfma_kernel<<<2048, 256, 0, stream>>>(t1, t2, out);
    }
}